// Round 1
// baseline (6024.775 us; speedup 1.0000x reference)
//
#include <hip/hip_runtime.h>
#include <math.h>

#define NN 100000
#define NE 1600000
#define INC 128
#define OC 64
#define ED 32

__device__ __forceinline__ float sigmoidf_(float z) {
    return 1.0f / (1.0f + __expf(-z));
}

// K1: y_l = x @ W_l   (thread per node; x row in VGPRs, W via wave-uniform s_load)
extern "C" __global__ void __launch_bounds__(256)
k_ylin(const float* __restrict__ x, const float* __restrict__ Wl,
       float* __restrict__ yl) {
    int i = blockIdx.x * 256 + threadIdx.x;
    if (i >= NN) return;
    float xr[INC];
    const float4* xp = reinterpret_cast<const float4*>(x + (size_t)i * INC);
#pragma unroll
    for (int k4 = 0; k4 < INC / 4; ++k4) {
        float4 v = xp[k4];
        xr[4 * k4 + 0] = v.x; xr[4 * k4 + 1] = v.y;
        xr[4 * k4 + 2] = v.z; xr[4 * k4 + 3] = v.w;
    }
    float* yp = yl + (size_t)i * OC;
#pragma unroll 1
    for (int j0 = 0; j0 < OC; j0 += 8) {
        float acc[8];
#pragma unroll
        for (int jj = 0; jj < 8; ++jj) acc[jj] = 0.0f;
#pragma unroll
        for (int k = 0; k < INC; ++k) {
            float xv = xr[k];
#pragma unroll
            for (int jj = 0; jj < 8; ++jj)
                acc[jj] = fmaf(xv, Wl[k * OC + j0 + jj], acc[jj]);
        }
#pragma unroll
        for (int jj = 0; jj < 8; ++jj) yp[j0 + jj] = acc[jj];
    }
}

// K2: scatter y_l[row[e]] into agg[col[e]], count edges per target.
// 64 lanes = 1 edge, lane = channel -> coalesced gather + coalesced atomics.
extern "C" __global__ void __launch_bounds__(256)
k_scatter(const int* __restrict__ rowv, const int* __restrict__ colv,
          const float* __restrict__ yl, float* __restrict__ agg,
          float* __restrict__ cnt) {
    int e = blockIdx.x * 4 + (threadIdx.x >> 6);
    if (e >= NE) return;
    int c = threadIdx.x & 63;
    int r = rowv[e], cl = colv[e];
    r = min(max(r, 0), NN - 1);
    cl = min(max(cl, 0), NN - 1);
    atomicAdd(&agg[(size_t)cl * OC + c], yl[(size_t)r * OC + c]);
    if (c == 0) atomicAdd(&cnt[cl], 1.0f);
}

// K3: out_pre = agg/max(cnt,1) + b_l + x @ W_r, in-place into agg buffer.
extern "C" __global__ void __launch_bounds__(256)
k_outpre(const float* __restrict__ x, const float* __restrict__ Wr,
         const float* __restrict__ bl, const float* __restrict__ cnt,
         float* __restrict__ agg) {
    int i = blockIdx.x * 256 + threadIdx.x;
    if (i >= NN) return;
    float xr[INC];
    const float4* xp = reinterpret_cast<const float4*>(x + (size_t)i * INC);
#pragma unroll
    for (int k4 = 0; k4 < INC / 4; ++k4) {
        float4 v = xp[k4];
        xr[4 * k4 + 0] = v.x; xr[4 * k4 + 1] = v.y;
        xr[4 * k4 + 2] = v.z; xr[4 * k4 + 3] = v.w;
    }
    float inv = 1.0f / fmaxf(cnt[i], 1.0f);
    float* op = agg + (size_t)i * OC;
#pragma unroll 1
    for (int j0 = 0; j0 < OC; j0 += 8) {
        float acc[8];
#pragma unroll
        for (int jj = 0; jj < 8; ++jj)
            acc[jj] = fmaf(op[j0 + jj], inv, bl[j0 + jj]);
#pragma unroll
        for (int k = 0; k < INC; ++k) {
            float xv = xr[k];
#pragma unroll
            for (int jj = 0; jj < 8; ++jj)
                acc[jj] = fmaf(xv, Wr[k * OC + j0 + jj], acc[jj]);
        }
#pragma unroll
        for (int jj = 0; jj < 8; ++jj) op[j0 + jj] = acc[jj];
    }
}

// K4: per-edge gating. thread = edge. ea = edge_attr@W_e + b_e;
// z = [out_pre[col] | ea] @ W_g + b_g; contrib = sigmoid(z)*ea -> atomic scatter.
// All weight accesses wave-uniform (s_load); comb kept in VGPRs with
// compile-time indices (fully unrolled).
extern "C" __global__ void __launch_bounds__(256)
k_gate(const int* __restrict__ colv, const float* __restrict__ eattr,
       const float* __restrict__ We, const float* __restrict__ be,
       const float* __restrict__ Wg, const float* __restrict__ bg,
       const float* __restrict__ outp, float* __restrict__ contrib) {
    int e = blockIdx.x * 256 + threadIdx.x;
    if (e >= NE) return;
    int cl = colv[e];
    cl = min(max(cl, 0), NN - 1);

    float ein[ED];
    const float4* ep = reinterpret_cast<const float4*>(eattr + (size_t)e * ED);
#pragma unroll
    for (int k4 = 0; k4 < ED / 4; ++k4) {
        float4 v = ep[k4];
        ein[4 * k4 + 0] = v.x; ein[4 * k4 + 1] = v.y;
        ein[4 * k4 + 2] = v.z; ein[4 * k4 + 3] = v.w;
    }

    float ea[OC];
#pragma unroll
    for (int j0 = 0; j0 < OC; j0 += 8) {
        float acc[8];
#pragma unroll
        for (int jj = 0; jj < 8; ++jj) acc[jj] = be[j0 + jj];
#pragma unroll
        for (int k = 0; k < ED; ++k) {
            float ev = ein[k];
#pragma unroll
            for (int jj = 0; jj < 8; ++jj)
                acc[jj] = fmaf(ev, We[k * OC + j0 + jj], acc[jj]);
        }
#pragma unroll
        for (int jj = 0; jj < 8; ++jj) ea[j0 + jj] = acc[jj];
    }

    float o[OC];
    const float4* op4 = reinterpret_cast<const float4*>(outp + (size_t)cl * OC);
#pragma unroll
    for (int k4 = 0; k4 < OC / 4; ++k4) {
        float4 v = op4[k4];
        o[4 * k4 + 0] = v.x; o[4 * k4 + 1] = v.y;
        o[4 * k4 + 2] = v.z; o[4 * k4 + 3] = v.w;
    }

    float* cb = contrib + (size_t)cl * OC;
#pragma unroll
    for (int j0 = 0; j0 < OC; j0 += 8) {
        float acc[8];
#pragma unroll
        for (int jj = 0; jj < 8; ++jj) acc[jj] = bg[j0 + jj];
#pragma unroll
        for (int k = 0; k < OC; ++k) {
            float ov = o[k];
#pragma unroll
            for (int jj = 0; jj < 8; ++jj)
                acc[jj] = fmaf(ov, Wg[k * OC + j0 + jj], acc[jj]);
        }
#pragma unroll
        for (int k = 0; k < OC; ++k) {
            float ev = ea[k];
#pragma unroll
            for (int jj = 0; jj < 8; ++jj)
                acc[jj] = fmaf(ev, Wg[(OC + k) * OC + j0 + jj], acc[jj]);
        }
#pragma unroll
        for (int jj = 0; jj < 8; ++jj) {
            float g = sigmoidf_(acc[jj]);
            atomicAdd(&cb[j0 + jj], g * ea[j0 + jj]);
        }
    }
}

// K5: BN batch stats (sum, sumsq per channel). Grid-stride keeps each
// thread's channel fixed (stride multiple of 64).
extern "C" __global__ void __launch_bounds__(256)
k_stats(const float* __restrict__ a, const float* __restrict__ b,
        float* __restrict__ stats) {
    __shared__ float ls[256], lq[256];
    int t = threadIdx.x;
    float s = 0.0f, q = 0.0f;
    for (size_t idx = (size_t)blockIdx.x * 256 + t; idx < (size_t)NN * OC;
         idx += (size_t)gridDim.x * 256) {
        float v = a[idx] + b[idx];
        s += v;
        q = fmaf(v, v, q);
    }
    ls[t] = s; lq[t] = q;
    __syncthreads();
    if (t < OC) {
        s = ls[t] + ls[t + 64] + ls[t + 128] + ls[t + 192];
        q = lq[t] + lq[t + 64] + lq[t + 128] + lq[t + 192];
        atomicAdd(&stats[t], s);
        atomicAdd(&stats[OC + t], q);
    }
}

// K6: BN normalize + residual(2x) + ReLU.
extern "C" __global__ void __launch_bounds__(256)
k_final(const float* __restrict__ a, const float* __restrict__ b,
        const float* __restrict__ stats, const float* __restrict__ gamma,
        const float* __restrict__ beta, float* __restrict__ out) {
    size_t idx = (size_t)blockIdx.x * 256 + threadIdx.x;
    if (idx >= (size_t)NN * OC) return;
    int c = (int)(idx & 63);
    float mu = stats[c] * (1.0f / NN);
    float var = stats[OC + c] * (1.0f / NN) - mu * mu;
    float v = a[idx] + b[idx];
    float y = fmaf(gamma[c] * (v - mu), rsqrtf(var + 1e-5f), beta[c]);
    out[idx] = fmaxf(2.0f * y, 0.0f);
}

extern "C" void kernel_launch(void* const* d_in, const int* in_sizes, int n_in,
                              void* d_out, int out_size, void* d_ws, size_t ws_size,
                              hipStream_t stream) {
    const float* x     = (const float*)d_in[0];
    const int*   ei    = (const int*)d_in[1];   // (2, NE) int32
    const float* eattr = (const float*)d_in[2];
    const float* Wl    = (const float*)d_in[3];
    const float* bl    = (const float*)d_in[4];
    const float* Wr    = (const float*)d_in[5];
    const float* We    = (const float*)d_in[6];
    const float* be    = (const float*)d_in[7];
    const float* Wg    = (const float*)d_in[8];
    const float* bg    = (const float*)d_in[9];
    const float* gamma = (const float*)d_in[10];
    const float* beta  = (const float*)d_in[11];
    float* out = (float*)d_out;

    // workspace layout (fp32 elems): agg/out_pre [NN*OC] | yl/contrib [NN*OC] | cnt [NN] | stats [128]
    float* agg   = (float*)d_ws;
    float* yl    = agg + (size_t)NN * OC;
    float* cnt   = yl + (size_t)NN * OC;
    float* stats = cnt + NN;

    const int* rowv = ei;
    const int* colv = ei + NE;

    hipMemsetAsync(agg, 0, (size_t)NN * OC * sizeof(float), stream);
    hipMemsetAsync(cnt, 0, (size_t)NN * sizeof(float), stream);
    hipMemsetAsync(stats, 0, 2 * OC * sizeof(float), stream);

    k_ylin<<<(NN + 255) / 256, 256, 0, stream>>>(x, Wl, yl);
    k_scatter<<<NE / 4, 256, 0, stream>>>(rowv, colv, yl, agg, cnt);
    k_outpre<<<(NN + 255) / 256, 256, 0, stream>>>(x, Wr, bl, cnt, agg);
    hipMemsetAsync(yl, 0, (size_t)NN * OC * sizeof(float), stream);  // -> contrib
    k_gate<<<(NE + 255) / 256, 256, 0, stream>>>(colv, eattr, We, be, Wg, bg, agg, yl);
    k_stats<<<2048, 256, 0, stream>>>(agg, yl, stats);
    k_final<<<((size_t)NN * OC + 255) / 256, 256, 0, stream>>>(agg, yl, stats, gamma, beta, out);
}

// Round 2
// 1337.921 us; speedup vs baseline: 4.5031x; 4.5031x over previous
//
#include <hip/hip_runtime.h>
#include <math.h>

#define NN 100000
#define NE 1600000
#define INC 128
#define OC 64
#define ED 32

__device__ __forceinline__ float sigmoidf_(float z) {
    return 1.0f / (1.0f + __expf(-z));
}

// K1: y_l = x @ W_l   (thread per node; x row in VGPRs, W via wave-uniform s_load)
extern "C" __global__ void __launch_bounds__(256)
k_ylin(const float* __restrict__ x, const float* __restrict__ Wl,
       float* __restrict__ yl) {
    int i = blockIdx.x * 256 + threadIdx.x;
    if (i >= NN) return;
    float xr[INC];
    const float4* xp = reinterpret_cast<const float4*>(x + (size_t)i * INC);
#pragma unroll
    for (int k4 = 0; k4 < INC / 4; ++k4) {
        float4 v = xp[k4];
        xr[4 * k4 + 0] = v.x; xr[4 * k4 + 1] = v.y;
        xr[4 * k4 + 2] = v.z; xr[4 * k4 + 3] = v.w;
    }
    float* yp = yl + (size_t)i * OC;
#pragma unroll 1
    for (int j0 = 0; j0 < OC; j0 += 8) {
        float acc[8];
#pragma unroll
        for (int jj = 0; jj < 8; ++jj) acc[jj] = 0.0f;
#pragma unroll
        for (int k = 0; k < INC; ++k) {
            float xv = xr[k];
#pragma unroll
            for (int jj = 0; jj < 8; ++jj)
                acc[jj] = fmaf(xv, Wl[k * OC + j0 + jj], acc[jj]);
        }
#pragma unroll
        for (int jj = 0; jj < 8; ++jj) yp[j0 + jj] = acc[jj];
    }
}

// K2: scatter y_l[row[e]] into agg[col[e]], count edges per target.
// 64 lanes = 1 edge, lane = channel -> coalesced gather + coalesced atomics.
extern "C" __global__ void __launch_bounds__(256)
k_scatter(const int* __restrict__ rowv, const int* __restrict__ colv,
          const float* __restrict__ yl, float* __restrict__ agg,
          float* __restrict__ cnt) {
    int e = blockIdx.x * 4 + (threadIdx.x >> 6);
    if (e >= NE) return;
    int c = threadIdx.x & 63;
    int r = rowv[e], cl = colv[e];
    r = min(max(r, 0), NN - 1);
    cl = min(max(cl, 0), NN - 1);
    atomicAdd(&agg[(size_t)cl * OC + c], yl[(size_t)r * OC + c]);
    if (c == 0) atomicAdd(&cnt[cl], 1.0f);
}

// K3: out_pre = agg/max(cnt,1) + b_l + x @ W_r, in-place into agg buffer.
extern "C" __global__ void __launch_bounds__(256)
k_outpre(const float* __restrict__ x, const float* __restrict__ Wr,
         const float* __restrict__ bl, const float* __restrict__ cnt,
         float* __restrict__ agg) {
    int i = blockIdx.x * 256 + threadIdx.x;
    if (i >= NN) return;
    float xr[INC];
    const float4* xp = reinterpret_cast<const float4*>(x + (size_t)i * INC);
#pragma unroll
    for (int k4 = 0; k4 < INC / 4; ++k4) {
        float4 v = xp[k4];
        xr[4 * k4 + 0] = v.x; xr[4 * k4 + 1] = v.y;
        xr[4 * k4 + 2] = v.z; xr[4 * k4 + 3] = v.w;
    }
    float inv = 1.0f / fmaxf(cnt[i], 1.0f);
    float* op = agg + (size_t)i * OC;
#pragma unroll 1
    for (int j0 = 0; j0 < OC; j0 += 8) {
        float acc[8];
#pragma unroll
        for (int jj = 0; jj < 8; ++jj)
            acc[jj] = fmaf(op[j0 + jj], inv, bl[j0 + jj]);
#pragma unroll
        for (int k = 0; k < INC; ++k) {
            float xv = xr[k];
#pragma unroll
            for (int jj = 0; jj < 8; ++jj)
                acc[jj] = fmaf(xv, Wr[k * OC + j0 + jj], acc[jj]);
        }
#pragma unroll
        for (int jj = 0; jj < 8; ++jj) op[j0 + jj] = acc[jj];
    }
}

// K3b: h[i] = out_pre[i] @ Wg_top + b_g  (node-dependent half of the gate
// pre-activation, hoisted out of the per-edge loop).
extern "C" __global__ void __launch_bounds__(256)
k_hpre(const float* __restrict__ outp, const float* __restrict__ Wg,
       const float* __restrict__ bg, float* __restrict__ h) {
    int i = blockIdx.x * 256 + threadIdx.x;
    if (i >= NN) return;
    float o[OC];
    const float4* op4 = reinterpret_cast<const float4*>(outp + (size_t)i * OC);
#pragma unroll
    for (int k4 = 0; k4 < OC / 4; ++k4) {
        float4 v = op4[k4];
        o[4 * k4 + 0] = v.x; o[4 * k4 + 1] = v.y;
        o[4 * k4 + 2] = v.z; o[4 * k4 + 3] = v.w;
    }
    float* hp = h + (size_t)i * OC;
#pragma unroll 1
    for (int j0 = 0; j0 < OC; j0 += 8) {
        float acc[8];
#pragma unroll
        for (int jj = 0; jj < 8; ++jj) acc[jj] = bg[j0 + jj];
#pragma unroll
        for (int k = 0; k < OC; ++k) {
            float ov = o[k];
#pragma unroll
            for (int jj = 0; jj < 8; ++jj)
                acc[jj] = fmaf(ov, Wg[k * OC + j0 + jj], acc[jj]);
        }
#pragma unroll
        for (int jj = 0; jj < 8; ++jj) hp[j0 + jj] = acc[jj];
    }
}

// K4: per-edge gating, one wave per 64 edges. Each lane computes its edge's
// 64 contrib values (weights via wave-uniform s_load), writes them into a
// rotation-swizzled LDS tile (2-way bank aliasing = free), then the wave
// scatters edge-by-edge with lane=channel -> coalesced atomics (k_scatter's
// proven-cheap pattern). Accumulates directly into agg (out_pre buffer).
extern "C" __global__ void __launch_bounds__(64)
k_gate(const int* __restrict__ colv, const float* __restrict__ eattr,
       const float* __restrict__ We, const float* __restrict__ be,
       const float* __restrict__ Wg, const float* __restrict__ h,
       float* __restrict__ agg) {
    __shared__ float tile[64][64];  // 16 KiB
    int lane = threadIdx.x;
    int e = blockIdx.x * 64 + lane;  // NE % 64 == 0, no tail
    int cl = colv[e];
    cl = min(max(cl, 0), NN - 1);

    float ein[ED];
    const float4* ep = reinterpret_cast<const float4*>(eattr + (size_t)e * ED);
#pragma unroll
    for (int k4 = 0; k4 < ED / 4; ++k4) {
        float4 v = ep[k4];
        ein[4 * k4 + 0] = v.x; ein[4 * k4 + 1] = v.y;
        ein[4 * k4 + 2] = v.z; ein[4 * k4 + 3] = v.w;
    }

    // ea = edge_attr @ W_e + b_e
    float ea[OC];
#pragma unroll
    for (int j0 = 0; j0 < OC; j0 += 8) {
        float acc[8];
#pragma unroll
        for (int jj = 0; jj < 8; ++jj) acc[jj] = be[j0 + jj];
#pragma unroll
        for (int k = 0; k < ED; ++k) {
            float ev = ein[k];
#pragma unroll
            for (int jj = 0; jj < 8; ++jj)
                acc[jj] = fmaf(ev, We[k * OC + j0 + jj], acc[jj]);
        }
#pragma unroll
        for (int jj = 0; jj < 8; ++jj) ea[j0 + jj] = acc[jj];
    }

    // z = h[col] + ea @ Wg_bot ; contrib = sigmoid(z) * ea -> swizzled LDS
    const float* hrow = h + (size_t)cl * OC;
#pragma unroll
    for (int j0 = 0; j0 < OC; j0 += 8) {
        float acc[8];
        const float4* hp = reinterpret_cast<const float4*>(hrow + j0);
        float4 h0 = hp[0], h1 = hp[1];
        acc[0] = h0.x; acc[1] = h0.y; acc[2] = h0.z; acc[3] = h0.w;
        acc[4] = h1.x; acc[5] = h1.y; acc[6] = h1.z; acc[7] = h1.w;
#pragma unroll
        for (int k = 0; k < OC; ++k) {
            float ev = ea[k];
#pragma unroll
            for (int jj = 0; jj < 8; ++jj)
                acc[jj] = fmaf(ev, Wg[(OC + k) * OC + j0 + jj], acc[jj]);
        }
#pragma unroll
        for (int jj = 0; jj < 8; ++jj) {
            float g = sigmoidf_(acc[jj]);
            tile[lane][(j0 + jj + lane) & 63] = g * ea[j0 + jj];
        }
    }

    // wave-synchronous (single wave per block): no barrier needed, compiler
    // inserts lgkmcnt waits for the LDS dependency.
#pragma unroll 4
    for (int t = 0; t < 64; ++t) {
        int ce = __shfl(cl, t);
        atomicAdd(&agg[(size_t)ce * OC + lane], tile[t][(lane + t) & 63]);
    }
}

// K5: BN batch stats (sum, sumsq per channel). Grid-stride keeps each
// thread's channel fixed (stride multiple of 64).
extern "C" __global__ void __launch_bounds__(256)
k_stats(const float* __restrict__ a, float* __restrict__ stats) {
    __shared__ float ls[256], lq[256];
    int t = threadIdx.x;
    float s = 0.0f, q = 0.0f;
    for (size_t idx = (size_t)blockIdx.x * 256 + t; idx < (size_t)NN * OC;
         idx += (size_t)gridDim.x * 256) {
        float v = a[idx];
        s += v;
        q = fmaf(v, v, q);
    }
    ls[t] = s; lq[t] = q;
    __syncthreads();
    if (t < OC) {
        s = ls[t] + ls[t + 64] + ls[t + 128] + ls[t + 192];
        q = lq[t] + lq[t + 64] + lq[t + 128] + lq[t + 192];
        atomicAdd(&stats[t], s);
        atomicAdd(&stats[OC + t], q);
    }
}

// K6: BN normalize + residual(2x) + ReLU.
extern "C" __global__ void __launch_bounds__(256)
k_final(const float* __restrict__ a, const float* __restrict__ stats,
        const float* __restrict__ gamma, const float* __restrict__ beta,
        float* __restrict__ out) {
    size_t idx = (size_t)blockIdx.x * 256 + threadIdx.x;
    if (idx >= (size_t)NN * OC) return;
    int c = (int)(idx & 63);
    float mu = stats[c] * (1.0f / NN);
    float var = stats[OC + c] * (1.0f / NN) - mu * mu;
    float v = a[idx];
    float y = fmaf(gamma[c] * (v - mu), rsqrtf(var + 1e-5f), beta[c]);
    out[idx] = fmaxf(2.0f * y, 0.0f);
}

extern "C" void kernel_launch(void* const* d_in, const int* in_sizes, int n_in,
                              void* d_out, int out_size, void* d_ws, size_t ws_size,
                              hipStream_t stream) {
    const float* x     = (const float*)d_in[0];
    const int*   ei    = (const int*)d_in[1];   // (2, NE) int32
    const float* eattr = (const float*)d_in[2];
    const float* Wl    = (const float*)d_in[3];
    const float* bl    = (const float*)d_in[4];
    const float* Wr    = (const float*)d_in[5];
    const float* We    = (const float*)d_in[6];
    const float* be    = (const float*)d_in[7];
    const float* Wg    = (const float*)d_in[8];
    const float* bg    = (const float*)d_in[9];
    const float* gamma = (const float*)d_in[10];
    const float* beta  = (const float*)d_in[11];
    float* out = (float*)d_out;

    // workspace (fp32 elems): agg/out_pre [NN*OC] | yl (then h) [NN*OC] | cnt [NN] | stats [128]
    float* agg   = (float*)d_ws;
    float* yl    = agg + (size_t)NN * OC;   // reused as h after k_outpre
    float* cnt   = yl + (size_t)NN * OC;
    float* stats = cnt + NN;
    float* h     = yl;  // yl is dead once k_scatter has consumed it

    const int* rowv = ei;
    const int* colv = ei + NE;

    hipMemsetAsync(agg, 0, (size_t)NN * OC * sizeof(float), stream);
    hipMemsetAsync(cnt, 0, (size_t)NN * sizeof(float), stream);
    hipMemsetAsync(stats, 0, 2 * OC * sizeof(float), stream);

    k_ylin<<<(NN + 255) / 256, 256, 0, stream>>>(x, Wl, yl);
    k_scatter<<<NE / 4, 256, 0, stream>>>(rowv, colv, yl, agg, cnt);
    k_outpre<<<(NN + 255) / 256, 256, 0, stream>>>(x, Wr, bl, cnt, agg);
    k_hpre<<<(NN + 255) / 256, 256, 0, stream>>>(agg, Wg, bg, h);
    k_gate<<<NE / 64, 64, 0, stream>>>(colv, eattr, We, be, Wg, h, agg);
    k_stats<<<2048, 256, 0, stream>>>(agg, stats);
    k_final<<<((size_t)NN * OC + 255) / 256, 256, 0, stream>>>(agg, stats, gamma, beta, out);
}

// Round 3
// 1092.192 us; speedup vs baseline: 5.5162x; 1.2250x over previous
//
#include <hip/hip_runtime.h>
#include <math.h>

#define NN 100000
#define NE 1600000
#define INC 128
#define OC 64
#define ED 32

__device__ __forceinline__ float sigmoidf_(float z) {
    return 1.0f / (1.0f + __expf(-z));
}

// K0: fuse gate weights. Wf = We @ Wg_bot (32x64), hb = be @ Wg_bot (64).
// z = h'[col] + eattr @ Wf, with h' = out_pre@Wg_top + bg + hb.
extern "C" __global__ void __launch_bounds__(256)
k_wfuse(const float* __restrict__ We, const float* __restrict__ be,
        const float* __restrict__ Wg, float* __restrict__ Wf,
        float* __restrict__ hb) {
    int idx = blockIdx.x * 256 + threadIdx.x;
    if (idx < ED * OC) {
        int d = idx >> 6, j = idx & 63;
        float acc = 0.0f;
#pragma unroll
        for (int k = 0; k < OC; ++k)
            acc = fmaf(We[d * OC + k], Wg[(OC + k) * OC + j], acc);
        Wf[idx] = acc;
    } else if (idx < ED * OC + OC) {
        int j = idx - ED * OC;
        float acc = 0.0f;
#pragma unroll
        for (int k = 0; k < OC; ++k)
            acc = fmaf(be[k], Wg[(OC + k) * OC + j], acc);
        hb[j] = acc;
    }
}

// K1: y_l = x @ W_l   (thread per node; x row in VGPRs, W via wave-uniform s_load)
extern "C" __global__ void __launch_bounds__(256)
k_ylin(const float* __restrict__ x, const float* __restrict__ Wl,
       float* __restrict__ yl) {
    int i = blockIdx.x * 256 + threadIdx.x;
    if (i >= NN) return;
    float xr[INC];
    const float4* xp = reinterpret_cast<const float4*>(x + (size_t)i * INC);
#pragma unroll
    for (int k4 = 0; k4 < INC / 4; ++k4) {
        float4 v = xp[k4];
        xr[4 * k4 + 0] = v.x; xr[4 * k4 + 1] = v.y;
        xr[4 * k4 + 2] = v.z; xr[4 * k4 + 3] = v.w;
    }
    float* yp = yl + (size_t)i * OC;
#pragma unroll 1
    for (int j0 = 0; j0 < OC; j0 += 8) {
        float acc[8];
#pragma unroll
        for (int jj = 0; jj < 8; ++jj) acc[jj] = 0.0f;
#pragma unroll
        for (int k = 0; k < INC; ++k) {
            float xv = xr[k];
#pragma unroll
            for (int jj = 0; jj < 8; ++jj)
                acc[jj] = fmaf(xv, Wl[k * OC + j0 + jj], acc[jj]);
        }
#pragma unroll
        for (int jj = 0; jj < 8; ++jj) yp[j0 + jj] = acc[jj];
    }
}

// K2: scatter y_l[row[e]] into agg[col[e]], count edges per target.
// 64 lanes = 1 edge, lane = channel -> coalesced gather + coalesced atomics.
extern "C" __global__ void __launch_bounds__(256)
k_scatter(const int* __restrict__ rowv, const int* __restrict__ colv,
          const float* __restrict__ yl, float* __restrict__ agg,
          float* __restrict__ cnt) {
    int e = blockIdx.x * 4 + (threadIdx.x >> 6);
    if (e >= NE) return;
    int c = threadIdx.x & 63;
    int r = rowv[e], cl = colv[e];
    r = min(max(r, 0), NN - 1);
    cl = min(max(cl, 0), NN - 1);
    atomicAdd(&agg[(size_t)cl * OC + c], yl[(size_t)r * OC + c]);
    if (c == 0) atomicAdd(&cnt[cl], 1.0f);
}

// K3: out_pre = agg/max(cnt,1) + b_l + x @ W_r, in-place into agg buffer.
extern "C" __global__ void __launch_bounds__(256)
k_outpre(const float* __restrict__ x, const float* __restrict__ Wr,
         const float* __restrict__ bl, const float* __restrict__ cnt,
         float* __restrict__ agg) {
    int i = blockIdx.x * 256 + threadIdx.x;
    if (i >= NN) return;
    float xr[INC];
    const float4* xp = reinterpret_cast<const float4*>(x + (size_t)i * INC);
#pragma unroll
    for (int k4 = 0; k4 < INC / 4; ++k4) {
        float4 v = xp[k4];
        xr[4 * k4 + 0] = v.x; xr[4 * k4 + 1] = v.y;
        xr[4 * k4 + 2] = v.z; xr[4 * k4 + 3] = v.w;
    }
    float inv = 1.0f / fmaxf(cnt[i], 1.0f);
    float* op = agg + (size_t)i * OC;
#pragma unroll 1
    for (int j0 = 0; j0 < OC; j0 += 8) {
        float acc[8];
#pragma unroll
        for (int jj = 0; jj < 8; ++jj)
            acc[jj] = fmaf(op[j0 + jj], inv, bl[j0 + jj]);
#pragma unroll
        for (int k = 0; k < INC; ++k) {
            float xv = xr[k];
#pragma unroll
            for (int jj = 0; jj < 8; ++jj)
                acc[jj] = fmaf(xv, Wr[k * OC + j0 + jj], acc[jj]);
        }
#pragma unroll
        for (int jj = 0; jj < 8; ++jj) op[j0 + jj] = acc[jj];
    }
}

// K3b: h[i] = out_pre[i] @ Wg_top + bg + hb  (node-dependent gate half +
// folded be@Wg_bot constant).
extern "C" __global__ void __launch_bounds__(256)
k_hpre(const float* __restrict__ outp, const float* __restrict__ Wg,
       const float* __restrict__ bg, const float* __restrict__ hb,
       float* __restrict__ h) {
    int i = blockIdx.x * 256 + threadIdx.x;
    if (i >= NN) return;
    float o[OC];
    const float4* op4 = reinterpret_cast<const float4*>(outp + (size_t)i * OC);
#pragma unroll
    for (int k4 = 0; k4 < OC / 4; ++k4) {
        float4 v = op4[k4];
        o[4 * k4 + 0] = v.x; o[4 * k4 + 1] = v.y;
        o[4 * k4 + 2] = v.z; o[4 * k4 + 3] = v.w;
    }
    float* hp = h + (size_t)i * OC;
#pragma unroll 1
    for (int j0 = 0; j0 < OC; j0 += 8) {
        float acc[8];
#pragma unroll
        for (int jj = 0; jj < 8; ++jj) acc[jj] = bg[j0 + jj] + hb[j0 + jj];
#pragma unroll
        for (int k = 0; k < OC; ++k) {
            float ov = o[k];
#pragma unroll
            for (int jj = 0; jj < 8; ++jj)
                acc[jj] = fmaf(ov, Wg[k * OC + j0 + jj], acc[jj]);
        }
#pragma unroll
        for (int jj = 0; jj < 8; ++jj) hp[j0 + jj] = acc[jj];
    }
}

// K4: per-edge gating, one wave per 64 edges, chunked by 16 channels.
// Per chunk: z = h'[col][c0..c0+15] + ein@Wf, ea = be + ein@We (weights via
// wave-uniform s_load); contrib = sigmoid(z)*ea -> 64x17-padded LDS tile
// (<=2-way banks = free); scatter 4 edges x 16 channels per wave-instruction
// (4x64B coalesced atomic segments) directly into agg.
// LDS 4.25KB/wave (was 16KB) -> occupancy limited by VGPR (~75%) not LDS.
extern "C" __global__ void __launch_bounds__(64)
k_gate(const int* __restrict__ colv, const float* __restrict__ eattr,
       const float* __restrict__ We, const float* __restrict__ be,
       const float* __restrict__ Wf, const float* __restrict__ h,
       float* __restrict__ agg) {
    __shared__ float tile[64][17];
    int lane = threadIdx.x;
    int e = blockIdx.x * 64 + lane;  // NE % 64 == 0, no tail
    int cl = colv[e];
    cl = min(max(cl, 0), NN - 1);

    float ein[ED];
    const float4* ep = reinterpret_cast<const float4*>(eattr + (size_t)e * ED);
#pragma unroll
    for (int k4 = 0; k4 < ED / 4; ++k4) {
        float4 v = ep[k4];
        ein[4 * k4 + 0] = v.x; ein[4 * k4 + 1] = v.y;
        ein[4 * k4 + 2] = v.z; ein[4 * k4 + 3] = v.w;
    }

    const float* hrow = h + (size_t)cl * OC;
#pragma unroll 1
    for (int c0 = 0; c0 < OC; c0 += 16) {
        float az[16], ae[16];
        const float4* hp = reinterpret_cast<const float4*>(hrow + c0);
#pragma unroll
        for (int q = 0; q < 4; ++q) {
            float4 v = hp[q];
            az[4 * q + 0] = v.x; az[4 * q + 1] = v.y;
            az[4 * q + 2] = v.z; az[4 * q + 3] = v.w;
        }
#pragma unroll
        for (int jj = 0; jj < 16; ++jj) ae[jj] = be[c0 + jj];
#pragma unroll
        for (int k = 0; k < ED; ++k) {
            float ev = ein[k];
#pragma unroll
            for (int jj = 0; jj < 16; ++jj) {
                az[jj] = fmaf(ev, Wf[k * OC + c0 + jj], az[jj]);
                ae[jj] = fmaf(ev, We[k * OC + c0 + jj], ae[jj]);
            }
        }
#pragma unroll
        for (int jj = 0; jj < 16; ++jj)
            tile[lane][jj] = sigmoidf_(az[jj]) * ae[jj];

        // wave-synchronous scatter of this chunk: 4 edges x 16 channels
        // per iteration (lane = 16*edge_sub + channel).
        int esub = lane >> 4;
        int ch = lane & 15;
#pragma unroll 4
        for (int t = 0; t < 16; ++t) {
            int src = 4 * t + esub;
            int ce = __shfl(cl, src);
            atomicAdd(&agg[(size_t)ce * OC + c0 + ch], tile[src][ch]);
        }
    }
}

// K5: BN batch stats (sum, sumsq per channel).
extern "C" __global__ void __launch_bounds__(256)
k_stats(const float* __restrict__ a, float* __restrict__ stats) {
    __shared__ float ls[256], lq[256];
    int t = threadIdx.x;
    float s = 0.0f, q = 0.0f;
    for (size_t idx = (size_t)blockIdx.x * 256 + t; idx < (size_t)NN * OC;
         idx += (size_t)gridDim.x * 256) {
        float v = a[idx];
        s += v;
        q = fmaf(v, v, q);
    }
    ls[t] = s; lq[t] = q;
    __syncthreads();
    if (t < OC) {
        s = ls[t] + ls[t + 64] + ls[t + 128] + ls[t + 192];
        q = lq[t] + lq[t + 64] + lq[t + 128] + lq[t + 192];
        atomicAdd(&stats[t], s);
        atomicAdd(&stats[OC + t], q);
    }
}

// K6: BN normalize + residual(2x) + ReLU.
extern "C" __global__ void __launch_bounds__(256)
k_final(const float* __restrict__ a, const float* __restrict__ stats,
        const float* __restrict__ gamma, const float* __restrict__ beta,
        float* __restrict__ out) {
    size_t idx = (size_t)blockIdx.x * 256 + threadIdx.x;
    if (idx >= (size_t)NN * OC) return;
    int c = (int)(idx & 63);
    float mu = stats[c] * (1.0f / NN);
    float var = stats[OC + c] * (1.0f / NN) - mu * mu;
    float v = a[idx];
    float y = fmaf(gamma[c] * (v - mu), rsqrtf(var + 1e-5f), beta[c]);
    out[idx] = fmaxf(2.0f * y, 0.0f);
}

extern "C" void kernel_launch(void* const* d_in, const int* in_sizes, int n_in,
                              void* d_out, int out_size, void* d_ws, size_t ws_size,
                              hipStream_t stream) {
    const float* x     = (const float*)d_in[0];
    const int*   ei    = (const int*)d_in[1];   // (2, NE) int32
    const float* eattr = (const float*)d_in[2];
    const float* Wl    = (const float*)d_in[3];
    const float* bl    = (const float*)d_in[4];
    const float* Wr    = (const float*)d_in[5];
    const float* We    = (const float*)d_in[6];
    const float* be    = (const float*)d_in[7];
    const float* Wg    = (const float*)d_in[8];
    const float* bg    = (const float*)d_in[9];
    const float* gamma = (const float*)d_in[10];
    const float* beta  = (const float*)d_in[11];
    float* out = (float*)d_out;

    // ws (fp32 elems): agg/out_pre [NN*OC] | yl->h [NN*OC] | cnt [NN] |
    //                  stats [128] | Wf [2048] | hb [64]
    float* agg   = (float*)d_ws;
    float* yl    = agg + (size_t)NN * OC;   // reused as h after k_scatter
    float* cnt   = yl + (size_t)NN * OC;
    float* stats = cnt + NN;
    float* Wf    = stats + 128;
    float* hb    = Wf + ED * OC;
    float* h     = yl;

    const int* rowv = ei;
    const int* colv = ei + NE;

    hipMemsetAsync(agg, 0, (size_t)NN * OC * sizeof(float), stream);
    hipMemsetAsync(cnt, 0, (size_t)NN * sizeof(float), stream);
    hipMemsetAsync(stats, 0, 2 * OC * sizeof(float), stream);

    k_wfuse<<<(ED * OC + OC + 255) / 256, 256, 0, stream>>>(We, be, Wg, Wf, hb);
    k_ylin<<<(NN + 255) / 256, 256, 0, stream>>>(x, Wl, yl);
    k_scatter<<<NE / 4, 256, 0, stream>>>(rowv, colv, yl, agg, cnt);
    k_outpre<<<(NN + 255) / 256, 256, 0, stream>>>(x, Wr, bl, cnt, agg);
    k_hpre<<<(NN + 255) / 256, 256, 0, stream>>>(agg, Wg, bg, hb, h);
    k_gate<<<NE / 64, 64, 0, stream>>>(colv, eattr, We, be, Wf, h, agg);
    k_stats<<<2048, 256, 0, stream>>>(agg, stats);
    k_final<<<((size_t)NN * OC + 255) / 256, 256, 0, stream>>>(agg, stats, gamma, beta, out);
}

// Round 4
// 922.909 us; speedup vs baseline: 6.5280x; 1.1834x over previous
//
#include <hip/hip_runtime.h>
#include <math.h>

#define NN 100000
#define NE 1600000
#define INC 128
#define OC 64
#define ED 32

__device__ __forceinline__ float sigmoidf_(float z) {
    return 1.0f / (1.0f + __expf(-z));
}

// K0: fuse gate weights. Wf = We @ Wg_bot (32x64), hb = be @ Wg_bot (64).
extern "C" __global__ void __launch_bounds__(256)
k_wfuse(const float* __restrict__ We, const float* __restrict__ be,
        const float* __restrict__ Wg, float* __restrict__ Wf,
        float* __restrict__ hb) {
    int idx = blockIdx.x * 256 + threadIdx.x;
    if (idx < ED * OC) {
        int d = idx >> 6, j = idx & 63;
        float acc = 0.0f;
#pragma unroll
        for (int k = 0; k < OC; ++k)
            acc = fmaf(We[d * OC + k], Wg[(OC + k) * OC + j], acc);
        Wf[idx] = acc;
    } else if (idx < ED * OC + OC) {
        int j = idx - ED * OC;
        float acc = 0.0f;
#pragma unroll
        for (int k = 0; k < OC; ++k)
            acc = fmaf(be[k], Wg[(OC + k) * OC + j], acc);
        hb[j] = acc;
    }
}

// K1: y_l = x @ W_l
extern "C" __global__ void __launch_bounds__(256)
k_ylin(const float* __restrict__ x, const float* __restrict__ Wl,
       float* __restrict__ yl) {
    int i = blockIdx.x * 256 + threadIdx.x;
    if (i >= NN) return;
    float xr[INC];
    const float4* xp = reinterpret_cast<const float4*>(x + (size_t)i * INC);
#pragma unroll
    for (int k4 = 0; k4 < INC / 4; ++k4) {
        float4 v = xp[k4];
        xr[4 * k4 + 0] = v.x; xr[4 * k4 + 1] = v.y;
        xr[4 * k4 + 2] = v.z; xr[4 * k4 + 3] = v.w;
    }
    float* yp = yl + (size_t)i * OC;
#pragma unroll 1
    for (int j0 = 0; j0 < OC; j0 += 8) {
        float acc[8];
#pragma unroll
        for (int jj = 0; jj < 8; ++jj) acc[jj] = 0.0f;
#pragma unroll
        for (int k = 0; k < INC; ++k) {
            float xv = xr[k];
#pragma unroll
            for (int jj = 0; jj < 8; ++jj)
                acc[jj] = fmaf(xv, Wl[k * OC + j0 + jj], acc[jj]);
        }
#pragma unroll
        for (int jj = 0; jj < 8; ++jj) yp[j0 + jj] = acc[jj];
    }
}

// CSR build step 1: histogram of target nodes (int atomics).
extern "C" __global__ void __launch_bounds__(256)
k_hist(const int* __restrict__ colv, int* __restrict__ cnti) {
    int e = blockIdx.x * 256 + threadIdx.x;
    if (e >= NE) return;
    int cl = colv[e];
    cl = min(max(cl, 0), NN - 1);
    atomicAdd(&cnti[cl], 1);
}

// CSR build step 2a: per-block exclusive scan (1024 elems/block).
extern "C" __global__ void __launch_bounds__(1024)
k_scanA(const int* __restrict__ cnti, int* __restrict__ cur,
        int* __restrict__ bsum) {
    __shared__ int s[1024];
    int t = threadIdx.x;
    int idx = blockIdx.x * 1024 + t;
    int v = (idx < NN) ? cnti[idx] : 0;
    s[t] = v;
    __syncthreads();
#pragma unroll
    for (int off = 1; off < 1024; off <<= 1) {
        int tmp = (t >= off) ? s[t - off] : 0;
        __syncthreads();
        s[t] += tmp;
        __syncthreads();
    }
    if (idx < NN) cur[idx] = s[t] - v;  // exclusive within block
    if (t == 1023) bsum[blockIdx.x] = s[1023];
}

// CSR build step 2b: scan the 98 block sums (single block).
extern "C" __global__ void __launch_bounds__(128)
k_scanB(int* __restrict__ bsum) {
    __shared__ int s[128];
    int t = threadIdx.x;
    int v = (t < 98) ? bsum[t] : 0;
    s[t] = v;
    __syncthreads();
#pragma unroll
    for (int off = 1; off < 128; off <<= 1) {
        int tmp = (t >= off) ? s[t - off] : 0;
        __syncthreads();
        s[t] += tmp;
        __syncthreads();
    }
    if (t < 98) bsum[t] = s[t] - v;  // exclusive
}

// CSR build step 2c: add block offsets -> cur[i] = global exclusive prefix.
extern "C" __global__ void __launch_bounds__(1024)
k_scanC(int* __restrict__ cur, const int* __restrict__ bsum) {
    int idx = blockIdx.x * 1024 + threadIdx.x;
    if (idx < NN) cur[idx] += bsum[blockIdx.x];
}

// CSR build step 3: bucket edges by target. After this, cur[i] == end(i)
// (== start(i+1)); start(i) = (i==0) ? 0 : cur[i-1].
extern "C" __global__ void __launch_bounds__(256)
k_bucket(const int* __restrict__ colv, int* __restrict__ cur,
         unsigned long long* __restrict__ ec) {
    int e = blockIdx.x * 256 + threadIdx.x;
    if (e >= NE) return;
    int cl = colv[e];
    cl = min(max(cl, 0), NN - 1);
    int pos = atomicAdd(&cur[cl], 1);
    ec[pos] = ((unsigned long long)(unsigned)cl << 32) | (unsigned)e;
}

// K2': mean-agg numerator, atomic-free. Wave per node, lane = channel;
// gather-sum yl rows over the node's contiguous bucket, one coalesced write.
extern "C" __global__ void __launch_bounds__(256)
k_agg(const unsigned long long* __restrict__ ec, const int* __restrict__ rowv,
      const int* __restrict__ cur, const float* __restrict__ yl,
      float* __restrict__ agg) {
    int i = blockIdx.x * 4 + (threadIdx.x >> 6);
    if (i >= NN) return;
    int c = threadIdx.x & 63;
    int start = (i == 0) ? 0 : cur[i - 1];
    int end = cur[i];
    float acc = 0.0f;
    int p = start;
    for (; p + 1 < end; p += 2) {
        unsigned long long a0 = ec[p], a1 = ec[p + 1];
        int r0 = rowv[(int)(a0 & 0xffffffffULL)];
        int r1 = rowv[(int)(a1 & 0xffffffffULL)];
        r0 = min(max(r0, 0), NN - 1);
        r1 = min(max(r1, 0), NN - 1);
        float v0 = yl[(size_t)r0 * OC + c];
        float v1 = yl[(size_t)r1 * OC + c];
        acc += v0;
        acc += v1;
    }
    if (p < end) {
        int r0 = rowv[(int)(ec[p] & 0xffffffffULL)];
        r0 = min(max(r0, 0), NN - 1);
        acc += yl[(size_t)r0 * OC + c];
    }
    agg[(size_t)i * OC + c] = acc;
}

// K3: out_pre = agg/max(deg,1) + b_l + x @ W_r, in-place into agg.
extern "C" __global__ void __launch_bounds__(256)
k_outpre(const float* __restrict__ x, const float* __restrict__ Wr,
         const float* __restrict__ bl, const int* __restrict__ cur,
         float* __restrict__ agg) {
    int i = blockIdx.x * 256 + threadIdx.x;
    if (i >= NN) return;
    float xr[INC];
    const float4* xp = reinterpret_cast<const float4*>(x + (size_t)i * INC);
#pragma unroll
    for (int k4 = 0; k4 < INC / 4; ++k4) {
        float4 v = xp[k4];
        xr[4 * k4 + 0] = v.x; xr[4 * k4 + 1] = v.y;
        xr[4 * k4 + 2] = v.z; xr[4 * k4 + 3] = v.w;
    }
    int deg = cur[i] - ((i == 0) ? 0 : cur[i - 1]);
    float inv = 1.0f / fmaxf((float)deg, 1.0f);
    float* op = agg + (size_t)i * OC;
#pragma unroll 1
    for (int j0 = 0; j0 < OC; j0 += 8) {
        float acc[8];
#pragma unroll
        for (int jj = 0; jj < 8; ++jj)
            acc[jj] = fmaf(op[j0 + jj], inv, bl[j0 + jj]);
#pragma unroll
        for (int k = 0; k < INC; ++k) {
            float xv = xr[k];
#pragma unroll
            for (int jj = 0; jj < 8; ++jj)
                acc[jj] = fmaf(xv, Wr[k * OC + j0 + jj], acc[jj]);
        }
#pragma unroll
        for (int jj = 0; jj < 8; ++jj) op[j0 + jj] = acc[jj];
    }
}

// K3b: h[i] = out_pre[i] @ Wg_top + bg + hb
extern "C" __global__ void __launch_bounds__(256)
k_hpre(const float* __restrict__ outp, const float* __restrict__ Wg,
       const float* __restrict__ bg, const float* __restrict__ hb,
       float* __restrict__ h) {
    int i = blockIdx.x * 256 + threadIdx.x;
    if (i >= NN) return;
    float o[OC];
    const float4* op4 = reinterpret_cast<const float4*>(outp + (size_t)i * OC);
#pragma unroll
    for (int k4 = 0; k4 < OC / 4; ++k4) {
        float4 v = op4[k4];
        o[4 * k4 + 0] = v.x; o[4 * k4 + 1] = v.y;
        o[4 * k4 + 2] = v.z; o[4 * k4 + 3] = v.w;
    }
    float* hp = h + (size_t)i * OC;
#pragma unroll 1
    for (int j0 = 0; j0 < OC; j0 += 8) {
        float acc[8];
#pragma unroll
        for (int jj = 0; jj < 8; ++jj) acc[jj] = bg[j0 + jj] + hb[j0 + jj];
#pragma unroll
        for (int k = 0; k < OC; ++k) {
            float ov = o[k];
#pragma unroll
            for (int jj = 0; jj < 8; ++jj)
                acc[jj] = fmaf(ov, Wg[k * OC + j0 + jj], acc[jj]);
        }
#pragma unroll
        for (int jj = 0; jj < 8; ++jj) hp[j0 + jj] = acc[jj];
    }
}

// K4: gating over CSR-sorted edges, one wave per 64 positions. Consecutive
// lanes share target nodes -> per 16-channel chunk, segmented reduction over
// sorted runs in LDS; one atomic per (run, chunk) instead of per edge.
extern "C" __global__ void __launch_bounds__(64)
k_gate(const unsigned long long* __restrict__ ec, const float* __restrict__ eattr,
       const float* __restrict__ We, const float* __restrict__ be,
       const float* __restrict__ Wf, const float* __restrict__ h,
       float* __restrict__ agg) {
    __shared__ float tile[64][17];
    __shared__ int cls[64];
    __shared__ int rls[64];
    int lane = threadIdx.x;
    unsigned long long ev = ec[blockIdx.x * 64 + lane];  // NE % 64 == 0
    int e = (int)(ev & 0xffffffffULL);
    int cl = (int)(ev >> 32);

    // run heads / lengths within this sorted 64-edge tile
    int clprev = __shfl_up(cl, 1);
    bool head = (lane == 0) || (cl != clprev);
    unsigned long long m = __ballot(head);
    unsigned long long rest = (lane < 63) ? (m >> (lane + 1)) : 0ULL;
    int runl = head ? (rest ? (__builtin_ctzll(rest) + 1) : (64 - lane)) : 0;
    cls[lane] = cl;
    rls[lane] = runl;

    float ein[ED];
    const float4* ep = reinterpret_cast<const float4*>(eattr + (size_t)e * ED);
#pragma unroll
    for (int k4 = 0; k4 < ED / 4; ++k4) {
        float4 v = ep[k4];
        ein[4 * k4 + 0] = v.x; ein[4 * k4 + 1] = v.y;
        ein[4 * k4 + 2] = v.z; ein[4 * k4 + 3] = v.w;
    }

    const float* hrow = h + (size_t)cl * OC;
    int esub = lane >> 4;
    int ch = lane & 15;
#pragma unroll 1
    for (int c0 = 0; c0 < OC; c0 += 16) {
        float az[16], ae[16];
        const float4* hp = reinterpret_cast<const float4*>(hrow + c0);
#pragma unroll
        for (int q = 0; q < 4; ++q) {
            float4 v = hp[q];
            az[4 * q + 0] = v.x; az[4 * q + 1] = v.y;
            az[4 * q + 2] = v.z; az[4 * q + 3] = v.w;
        }
#pragma unroll
        for (int jj = 0; jj < 16; ++jj) ae[jj] = be[c0 + jj];
#pragma unroll
        for (int k = 0; k < ED; ++k) {
            float evv = ein[k];
#pragma unroll
            for (int jj = 0; jj < 16; ++jj) {
                az[jj] = fmaf(evv, Wf[k * OC + c0 + jj], az[jj]);
                ae[jj] = fmaf(evv, We[k * OC + c0 + jj], ae[jj]);
            }
        }
#pragma unroll
        for (int jj = 0; jj < 16; ++jj)
            tile[lane][jj] = sigmoidf_(az[jj]) * ae[jj];

        // segmented scatter: head lanes sum their run, one atomic per run.
#pragma unroll 1
        for (int t = 0; t < 16; ++t) {
            int r = 4 * t + esub;
            int len = rls[r];
            if (len) {
                float ssum = tile[r][ch];
                for (int q = 1; q < len; ++q) ssum += tile[r + q][ch];
                atomicAdd(&agg[(size_t)cls[r] * OC + c0 + ch], ssum);
            }
        }
    }
}

// K5: BN batch stats.
extern "C" __global__ void __launch_bounds__(256)
k_stats(const float* __restrict__ a, float* __restrict__ stats) {
    __shared__ float ls[256], lq[256];
    int t = threadIdx.x;
    float s = 0.0f, q = 0.0f;
    for (size_t idx = (size_t)blockIdx.x * 256 + t; idx < (size_t)NN * OC;
         idx += (size_t)gridDim.x * 256) {
        float v = a[idx];
        s += v;
        q = fmaf(v, v, q);
    }
    ls[t] = s; lq[t] = q;
    __syncthreads();
    if (t < OC) {
        s = ls[t] + ls[t + 64] + ls[t + 128] + ls[t + 192];
        q = lq[t] + lq[t + 64] + lq[t + 128] + lq[t + 192];
        atomicAdd(&stats[t], s);
        atomicAdd(&stats[OC + t], q);
    }
}

// K6: BN normalize + residual(2x) + ReLU.
extern "C" __global__ void __launch_bounds__(256)
k_final(const float* __restrict__ a, const float* __restrict__ stats,
        const float* __restrict__ gamma, const float* __restrict__ beta,
        float* __restrict__ out) {
    size_t idx = (size_t)blockIdx.x * 256 + threadIdx.x;
    if (idx >= (size_t)NN * OC) return;
    int c = (int)(idx & 63);
    float mu = stats[c] * (1.0f / NN);
    float var = stats[OC + c] * (1.0f / NN) - mu * mu;
    float v = a[idx];
    float y = fmaf(gamma[c] * (v - mu), rsqrtf(var + 1e-5f), beta[c]);
    out[idx] = fmaxf(2.0f * y, 0.0f);
}

extern "C" void kernel_launch(void* const* d_in, const int* in_sizes, int n_in,
                              void* d_out, int out_size, void* d_ws, size_t ws_size,
                              hipStream_t stream) {
    const float* x     = (const float*)d_in[0];
    const int*   ei    = (const int*)d_in[1];   // (2, NE) int32
    const float* eattr = (const float*)d_in[2];
    const float* Wl    = (const float*)d_in[3];
    const float* bl    = (const float*)d_in[4];
    const float* Wr    = (const float*)d_in[5];
    const float* We    = (const float*)d_in[6];
    const float* be    = (const float*)d_in[7];
    const float* Wg    = (const float*)d_in[8];
    const float* bg    = (const float*)d_in[9];
    const float* gamma = (const float*)d_in[10];
    const float* beta  = (const float*)d_in[11];
    float* out = (float*)d_out;

    // ws (fp32 slots): agg[6.4M] | h/yl[6.4M] | ec[1.6M u64 = 3.2M] |
    //                  cnti_cur[100k i32] | bsum[128 i32] | stats[128] |
    //                  Wf[2048] | hb[64]   (~65 MB total)
    float* agg = (float*)d_ws;
    float* yl  = agg + (size_t)NN * OC;      // reused as h after k_agg
    unsigned long long* ec = (unsigned long long*)(yl + (size_t)NN * OC);
    int* cur   = (int*)(ec + (size_t)NE);
    int* bsum  = cur + NN;
    float* stats = (float*)(bsum + 128);
    float* Wf  = stats + 128;
    float* hb  = Wf + ED * OC;
    float* h   = yl;

    const int* rowv = ei;
    const int* colv = ei + NE;

    hipMemsetAsync(cur, 0, NN * sizeof(int), stream);
    hipMemsetAsync(stats, 0, 2 * OC * sizeof(float), stream);

    k_wfuse<<<(ED * OC + OC + 255) / 256, 256, 0, stream>>>(We, be, Wg, Wf, hb);
    k_ylin<<<(NN + 255) / 256, 256, 0, stream>>>(x, Wl, yl);
    // CSR build (hist into cur, scanned in place)
    k_hist<<<(NE + 255) / 256, 256, 0, stream>>>(colv, cur);
    k_scanA<<<98, 1024, 0, stream>>>(cur, cur, bsum);
    k_scanB<<<1, 128, 0, stream>>>(bsum);
    k_scanC<<<98, 1024, 0, stream>>>(cur, bsum);
    k_bucket<<<(NE + 255) / 256, 256, 0, stream>>>(colv, cur, ec);
    // atomic-free mean-agg numerator
    k_agg<<<(NN + 3) / 4, 256, 0, stream>>>(ec, rowv, cur, yl, agg);
    k_outpre<<<(NN + 255) / 256, 256, 0, stream>>>(x, Wr, bl, cur, agg);
    k_hpre<<<(NN + 255) / 256, 256, 0, stream>>>(agg, Wg, bg, hb, h);
    k_gate<<<NE / 64, 64, 0, stream>>>(ec, eattr, We, be, Wf, h, agg);
    k_stats<<<2048, 256, 0, stream>>>(agg, stats);
    k_final<<<((size_t)NN * OC + 255) / 256, 256, 0, stream>>>(agg, stats, gamma, beta, out);
}